// Round 6
// baseline (248.638 us; speedup 1.0000x reference)
//
#include <hip/hip_runtime.h>

#define BATCH    8192
#define CTX      32
#define ROUTES   24
#define EDIM     128
#define NSLICE   24
#define WPB      4
#define NBLOCKS  (BATCH / WPB)
#define NPRE     256                 // L3-priming streamer blocks
#define PRE_THREADS (NPRE * 256)

typedef float f4 __attribute__((ext_vector_type(4)));

// Single kernel, two block roles:
//  - blocks [0, NPRE): stream input_embed + inner_node_embed sequentially.
//    The 400 MB ws-poison fill right before this kernel thrashes L3, so the
//    tables are HBM-cold every launch; streaming them re-primes the
//    memory-side 256 MB Infinity Cache at full streaming BW while the gather
//    blocks run, converting their random misses from HBM (~900 cyc) to L3
//    hits (~400 cyc). The gather is miss-latency-limited, so halving miss
//    latency ~doubles its bandwidth.
//  - blocks [NPRE, NPRE+NBLOCKS): round-2 gather/dot/loss structure
//    (one wave per row, half-wave float4 rows, butterfly reductions).
__global__ __launch_bounds__(256, 8) void tale_fused(
    const int* __restrict__ context,            // (B, C)
    const int* __restrict__ route,              // (B, R)
    const int* __restrict__ lr,                 // (B, R)
    const int* __restrict__ slice_idx,          // (B,)
    const float* __restrict__ input_embed,      // (NUM_LOC, E)
    const float* __restrict__ inner_node_embed, // (NUM_INNER+1, E)
    const float* __restrict__ slice_node_embed, // (NSLICE, E)
    float* __restrict__ out)
{
    if (blockIdx.x < NPRE) {
        // ---- L3-priming streamers ----
        const f4* t1 = reinterpret_cast<const f4*>(input_embed);
        const f4* t2 = reinterpret_cast<const f4*>(inner_node_embed);
        const unsigned tid = blockIdx.x * 256 + threadIdx.x;
        const size_t n1 = (size_t)100000 * 32;      // input_embed  in f4 units
        const size_t n2 = (size_t)200001 * 32;      // inner table  in f4 units
        f4 s = (f4)(0.f);
        for (size_t i = tid; i < n1; i += PRE_THREADS) s += t1[i];
        for (size_t i = tid; i < n2; i += PRE_THREADS) s += t2[i];
        float r = s.x + s.y + s.z + s.w;
        __asm__ volatile("" :: "v"(r));             // keep the loads alive
        return;
    }

    const int tid  = threadIdx.x;
    const int lane = tid & 63;
    const int half = lane >> 5;        // 0 = lower half, 1 = upper half
    const int sub  = lane & 31;        // owns dims 4*sub .. 4*sub+3
    const int w    = tid >> 6;
    const int b    = (blockIdx.x - NPRE) * WPB + w;

    __shared__ float bs[WPB];

    // ---- per-row indices (one per lane, broadcast via shuffle) ----
    int cidx = 0, ridx = 0, lridx = 0;
    if (lane < CTX) cidx = context[b * CTX + lane];
    if (lane < ROUTES) {
        ridx  = route[b * ROUTES + lane];
        lridx = lr[b * ROUTES + lane];
    }
    const int si = slice_idx[b];

    // ---- context embedding sum ----
    f4 acc = (f4)(0.f);
    #pragma unroll
    for (int i = 0; i < 16; ++i) {
        const int idx = __shfl(cidx, i + (half << 4));
        const f4 v = *reinterpret_cast<const f4*>(
            input_embed + (size_t)idx * EDIM + (sub << 2));
        acc += v;
    }
    acc.x += __shfl_xor(acc.x, 32);
    acc.y += __shfl_xor(acc.y, 32);
    acc.z += __shfl_xor(acc.z, 32);
    acc.w += __shfl_xor(acc.w, 32);
    // lane now holds ctx[4*sub .. 4*sub+3]

    // ---- route products: dots (2i, 2i+1) in the two halves ----
    float prodv = 1.f;
    #pragma unroll
    for (int i = 0; i < 12; ++i) {
        const int d   = 2 * i + half;
        const int idx = __shfl(ridx, d);
        const int l   = __shfl(lridx, d);
        const f4 v = *reinterpret_cast<const f4*>(
            inner_node_embed + (size_t)idx * EDIM + (sub << 2));
        float p = v.x * acc.x + v.y * acc.y + v.z * acc.z + v.w * acc.w;
        p += __shfl_xor(p, 16);
        p += __shfl_xor(p, 8);
        p += __shfl_xor(p, 4);
        p += __shfl_xor(p, 2);
        p += __shfl_xor(p, 1);          // full dot, uniform within half
        const float sg = 1.f / (1.f + __expf(-p));
        float h = l ? sg : (1.f - sg);
        if (idx == 0) h = 1.f;          // padded route position
        prodv *= h;
    }
    prodv *= __shfl_xor(prodv, 32);     // even-half * odd-half products

    // ---- slice softmax: two online chains (even/odd slices) ----
    float m = -3.0e38f, den = 0.f, selv = 0.f;
    #pragma unroll
    for (int i = 0; i < 12; ++i) {
        const int s = 2 * i + half;
        const float4 v = *reinterpret_cast<const float4*>(
            slice_node_embed + s * EDIM + (sub << 2));
        float p = v.x * acc.x + v.y * acc.y + v.z * acc.z + v.w * acc.w;
        p += __shfl_xor(p, 16);
        p += __shfl_xor(p, 8);
        p += __shfl_xor(p, 4);
        p += __shfl_xor(p, 2);
        p += __shfl_xor(p, 1);
        const float mN = fmaxf(m, p);
        den = den * __expf(m - mN) + __expf(p - mN);
        m = mN;
        if (s == si) selv = p;
    }
    const float m_o   = __shfl_xor(m, 32);
    const float den_o = __shfl_xor(den, 32);
    const float M     = fmaxf(m, m_o);
    const float dtot  = den * __expf(m - M) + den_o * __expf(m_o - M);
    const float sel   = __shfl(selv, (si & 1) << 5);
    const float slice_pre = __expf(sel - M) / dtot;

    const float pr = slice_pre * prodv;

    if (lane == 0) bs[w] = pr;
    __syncthreads();
    if (tid == 0) {
        const float s = bs[0] + bs[1] + bs[2] + bs[3];
        // out accumulates (1/NBLOCKS - blockSum/B) over blocks -> 1 - mean
        atomicAdd(out, 1.0f / NBLOCKS - s * (1.0f / BATCH));
    }
}

extern "C" void kernel_launch(void* const* d_in, const int* in_sizes, int n_in,
                              void* d_out, int out_size, void* d_ws, size_t ws_size,
                              hipStream_t stream)
{
    const int*   context          = (const int*)  d_in[0];
    const int*   route            = (const int*)  d_in[1];
    const int*   lr               = (const int*)  d_in[2];
    const int*   slice_idx        = (const int*)  d_in[3];
    const float* input_embed      = (const float*)d_in[4];
    const float* inner_node_embed = (const float*)d_in[5];
    const float* slice_node_embed = (const float*)d_in[6];
    float* out = (float*)d_out;

    // d_out is poisoned 0xAA before every launch; zero it, then blocks
    // atomic-accumulate so the final value is 1 - mean.
    hipMemsetAsync(out, 0, sizeof(float), stream);

    tale_fused<<<NPRE + NBLOCKS, 64 * WPB, 0, stream>>>(
        context, route, lr, slice_idx,
        input_embed, inner_node_embed, slice_node_embed, out);
}

// Round 7
// 238.751 us; speedup vs baseline: 1.0414x; 1.0414x over previous
//
#include <hip/hip_runtime.h>

#define BATCH    8192
#define CTX      32
#define ROUTES   24
#define EDIM     128
#define NSLICE   24
#define WPB      4
#define NBLOCKS  (BATCH / WPB)

typedef float f4 __attribute__((ext_vector_type(4)));

// ---------------- K0: sequenced L3 prime ----------------------------------
// The harness's 400 MB ws-poison fill thrashes the 256 MB Infinity Cache
// right before our launch, so both gather tables are HBM-cold. Streaming
// them in address order (normal cached loads -> memory-side L3 allocates)
// costs ~154 MB @ streaming rate, and runs to completion BEFORE the gather
// kernel, so the gather kernel sees only L3 hits and never mixes random
// HBM misses with the stream (round 6 showed mixing pins everything at
// the ~1.8 TB/s random rate).
__global__ __launch_bounds__(256) void tale_prime(
    const float* __restrict__ input_embed,      // (100000, 128)
    const float* __restrict__ inner_node_embed) // (200001, 128)
{
    const f4* t1 = reinterpret_cast<const f4*>(input_embed);
    const f4* t2 = reinterpret_cast<const f4*>(inner_node_embed);
    const size_t n1 = (size_t)100000 * 32;      // f4 elements
    const size_t n2 = (size_t)200001 * 32;
    const size_t stride = (size_t)gridDim.x * blockDim.x;
    const size_t base = (size_t)blockIdx.x * blockDim.x + threadIdx.x;
    f4 s = (f4)(0.f);
    for (size_t j = base; j < n1; j += stride) s += t1[j];
    for (size_t j = base; j < n2; j += stride) s += t2[j];
    float r = s.x + s.y + s.z + s.w;
    __asm__ volatile("" :: "v"(r));             // keep the loads alive
}

// ---------------- K1: round-2 gather/dot/loss kernel (fastest so far) ------
// One wave per batch row; lanes split into two 32-lane halves; each half
// owns one full E=128 row per float4 load (32 x 16B = 512B coalesced).
// Butterfly reductions within a half reduce TWO dots per tree.
__global__ __launch_bounds__(256, 8) void tale_fused(
    const int* __restrict__ context,            // (B, C)
    const int* __restrict__ route,              // (B, R)
    const int* __restrict__ lr,                 // (B, R)
    const int* __restrict__ slice_idx,          // (B,)
    const float* __restrict__ input_embed,      // (NUM_LOC, E)
    const float* __restrict__ inner_node_embed, // (NUM_INNER+1, E)
    const float* __restrict__ slice_node_embed, // (NSLICE, E)
    float* __restrict__ out)
{
    const int tid  = threadIdx.x;
    const int lane = tid & 63;
    const int half = lane >> 5;        // 0 = lower half, 1 = upper half
    const int sub  = lane & 31;        // owns dims 4*sub .. 4*sub+3
    const int w    = tid >> 6;
    const int b    = blockIdx.x * WPB + w;

    __shared__ float bs[WPB];

    int cidx = 0, ridx = 0, lridx = 0;
    if (lane < CTX) cidx = context[b * CTX + lane];
    if (lane < ROUTES) {
        ridx  = route[b * ROUTES + lane];
        lridx = lr[b * ROUTES + lane];
    }
    const int si = slice_idx[b];

    // ---- context embedding sum ----
    f4 acc = (f4)(0.f);
    #pragma unroll
    for (int i = 0; i < 16; ++i) {
        const int idx = __shfl(cidx, i + (half << 4));
        const f4 v = *reinterpret_cast<const f4*>(
            input_embed + (size_t)idx * EDIM + (sub << 2));
        acc += v;
    }
    acc.x += __shfl_xor(acc.x, 32);
    acc.y += __shfl_xor(acc.y, 32);
    acc.z += __shfl_xor(acc.z, 32);
    acc.w += __shfl_xor(acc.w, 32);
    // lane now holds ctx[4*sub .. 4*sub+3]

    // ---- route products ----
    float prodv = 1.f;
    #pragma unroll
    for (int i = 0; i < 12; ++i) {
        const int d   = 2 * i + half;
        const int idx = __shfl(ridx, d);
        const int l   = __shfl(lridx, d);
        const f4 v = *reinterpret_cast<const f4*>(
            inner_node_embed + (size_t)idx * EDIM + (sub << 2));
        float p = v.x * acc.x + v.y * acc.y + v.z * acc.z + v.w * acc.w;
        p += __shfl_xor(p, 16);
        p += __shfl_xor(p, 8);
        p += __shfl_xor(p, 4);
        p += __shfl_xor(p, 2);
        p += __shfl_xor(p, 1);
        const float sg = 1.f / (1.f + __expf(-p));
        float h = l ? sg : (1.f - sg);
        if (idx == 0) h = 1.f;          // padded route position
        prodv *= h;
    }
    prodv *= __shfl_xor(prodv, 32);

    // ---- slice softmax: two online chains (even/odd slices) ----
    float m = -3.0e38f, den = 0.f, selv = 0.f;
    #pragma unroll
    for (int i = 0; i < 12; ++i) {
        const int s = 2 * i + half;
        const float4 v = *reinterpret_cast<const float4*>(
            slice_node_embed + s * EDIM + (sub << 2));
        float p = v.x * acc.x + v.y * acc.y + v.z * acc.z + v.w * acc.w;
        p += __shfl_xor(p, 16);
        p += __shfl_xor(p, 8);
        p += __shfl_xor(p, 4);
        p += __shfl_xor(p, 2);
        p += __shfl_xor(p, 1);
        const float mN = fmaxf(m, p);
        den = den * __expf(m - mN) + __expf(p - mN);
        m = mN;
        if (s == si) selv = p;
    }
    const float m_o   = __shfl_xor(m, 32);
    const float den_o = __shfl_xor(den, 32);
    const float M     = fmaxf(m, m_o);
    const float dtot  = den * __expf(m - M) + den_o * __expf(m_o - M);
    const float sel   = __shfl(selv, (si & 1) << 5);
    const float slice_pre = __expf(sel - M) / dtot;

    const float pr = slice_pre * prodv;

    if (lane == 0) bs[w] = pr;
    __syncthreads();
    if (tid == 0) {
        const float s = bs[0] + bs[1] + bs[2] + bs[3];
        atomicAdd(out, 1.0f / NBLOCKS - s * (1.0f / BATCH));
    }
}

extern "C" void kernel_launch(void* const* d_in, const int* in_sizes, int n_in,
                              void* d_out, int out_size, void* d_ws, size_t ws_size,
                              hipStream_t stream)
{
    const int*   context          = (const int*)  d_in[0];
    const int*   route            = (const int*)  d_in[1];
    const int*   lr               = (const int*)  d_in[2];
    const int*   slice_idx        = (const int*)  d_in[3];
    const float* input_embed      = (const float*)d_in[4];
    const float* inner_node_embed = (const float*)d_in[5];
    const float* slice_node_embed = (const float*)d_in[6];
    float* out = (float*)d_out;

    hipMemsetAsync(out, 0, sizeof(float), stream);

    // Phase 1: prime L3 with both tables (completes before phase 2 starts).
    tale_prime<<<2048, 256, 0, stream>>>(input_embed, inner_node_embed);

    // Phase 2: gather/dot/loss, now served from a warm L3.
    tale_fused<<<NBLOCKS, 64 * WPB, 0, stream>>>(
        context, route, lr, slice_idx,
        input_embed, inner_node_embed, slice_node_embed, out);
}